// Round 3
// baseline (38.065 us; speedup 1.0000x reference)
//
#include <hip/hip_runtime.h>
#include <hip/hip_bf16.h>
#include <math.h>

typedef unsigned short u16;
typedef __attribute__((ext_vector_type(8))) short bf16x8;
typedef __attribute__((ext_vector_type(4))) float f32x4;

#define NB 128
#define ND 1024
#define NO 512
#define NK3 1536
#define EPSV 1e-5f
#define SCALEQK 0.04419417382415922f   // 1/sqrt(512)
#define LOG2E 1.4426950408889634f

static __device__ __forceinline__ float fast_exp2(float v) {
#if __has_builtin(__builtin_amdgcn_exp2f)
  return __builtin_amdgcn_exp2f(v);
#else
  return exp2f(v);
#endif
}
static __device__ __forceinline__ float fast_rcp(float v) {
#if __has_builtin(__builtin_amdgcn_rcpf)
  return __builtin_amdgcn_rcpf(v);
#else
  return 1.f / v;
#endif
}

static __device__ __forceinline__ u16 bf16_rtn(float f) {
  unsigned u = __float_as_uint(f);
  return (u16)((u + 0x7FFFu + ((u >> 16) & 1u)) >> 16);
}
static __device__ __forceinline__ void bf16_split(float f, u16& h, u16& l) {
  h = bf16_rtn(f);
  l = bf16_rtn(f - __uint_as_float(((unsigned)h) << 16));
}
static __device__ __forceinline__ float asinh_fast(float x) {
  const float ax = fabsf(x);
  const float s = sqrtf(fmaf(ax, ax, 1.f));
  return copysignf(__logf(ax + s), x);
}
static __device__ __forceinline__ float tanh_fast(float x) {
  // 1 - 2/(e^{2x}+1); saturates correctly at +-1
  return 1.f - 2.f * fast_rcp(fast_exp2(x * (2.f * LOG2E)) + 1.f);
}
static __device__ __forceinline__ float sig_fast(float x) {
  return fast_rcp(1.f + fast_exp2(-x * LOG2E));
}

// =============== shared MFMA GEMM tile: 128 rows x 64 cols, NCH k-chunks of 64 ===============
// bf16 hi/lo 3-pass emulated fp32; LDS XOR-swizzled (byte ^= (row&7)<<4).
// AMODE: 0 = pre-split u16 (Ah/Al), 1 = fp32 inline split, 2 = fp32 asinh + split
// WMODE: 0 = plain fp32 weights W0, 1 = tanh(W0)*sigmoid(W1)
// ATOMIC: 0 = plain store, 1 = atomicAdd (+bias if non-null)
template <int AMODE, int WMODE, int ATOMIC, int NCH>
static __device__ __forceinline__ void gemm_tile(
    const float* __restrict__ Xf, const u16* __restrict__ Ah,
    const u16* __restrict__ Al, int lda, const float* __restrict__ W0,
    const float* __restrict__ W1, const float* __restrict__ bias,
    float* __restrict__ outp, int o0, int k0, char* smem) {
  u16* AshH = (u16*)smem;                // 16 KB
  u16* AshL = (u16*)(smem + 16384);      // 16 KB
  u16* BshH = (u16*)(smem + 32768);      // 8 KB
  u16* BshL = (u16*)(smem + 40960);      // 8 KB
  const int t = threadIdx.x;
  const int lane = t & 63;
  const int w = t >> 6;
  const f32x4 vz = {0.f, 0.f, 0.f, 0.f};
  f32x4 acc[2][4];
#pragma unroll
  for (int m = 0; m < 2; ++m)
#pragma unroll
    for (int n = 0; n < 4; ++n) acc[m][n] = vz;

#pragma unroll
  for (int c = 0; c < NCH; ++c) {
    const int kc = k0 + c * 64;
    if (c) __syncthreads();
    // ---- stage A: 128 rows x 64 k ----
    {
      const int row = t >> 1, half = t & 1;
      const int swz = (row & 7) << 4;
      if (AMODE == 0) {
        const u16* gh = Ah + (size_t)row * lda + kc + half * 32;
        const u16* gl = Al + (size_t)row * lda + kc + half * 32;
#pragma unroll
        for (int jj = 0; jj < 4; ++jj) {
          const uint4 vh = *(const uint4*)(gh + jj * 8);
          const uint4 vl = *(const uint4*)(gl + jj * 8);
          const int byte = (row * 128 + half * 64 + jj * 16) ^ swz;
          *(uint4*)((char*)AshH + byte) = vh;
          *(uint4*)((char*)AshL + byte) = vl;
        }
      } else {
        const float* gx = Xf + (size_t)row * lda + kc + half * 32;
#pragma unroll
        for (int jj = 0; jj < 4; ++jj) {
          const float4 v0 = *(const float4*)(gx + jj * 8);
          const float4 v1 = *(const float4*)(gx + jj * 8 + 4);
          float e[8] = {v0.x, v0.y, v0.z, v0.w, v1.x, v1.y, v1.z, v1.w};
          unsigned hp[4], lp[4];
#pragma unroll
          for (int i = 0; i < 4; ++i) {
            float a0 = e[2 * i], a1 = e[2 * i + 1];
            if (AMODE == 2) { a0 = asinh_fast(a0); a1 = asinh_fast(a1); }
            u16 h0, l0, h1, l1;
            bf16_split(a0, h0, l0);
            bf16_split(a1, h1, l1);
            hp[i] = (unsigned)h0 | ((unsigned)h1 << 16);
            lp[i] = (unsigned)l0 | ((unsigned)l1 << 16);
          }
          const int byte = (row * 128 + half * 64 + jj * 16) ^ swz;
          *(uint4*)((char*)AshH + byte) = make_uint4(hp[0], hp[1], hp[2], hp[3]);
          *(uint4*)((char*)AshL + byte) = make_uint4(lp[0], lp[1], lp[2], lp[3]);
        }
      }
    }
    // ---- stage B transposed: Bsh[col][k], 64 cols x 64 k ----
#pragma unroll
    for (int s2 = 0; s2 < 2; ++s2) {
      const int s = t + s2 * 256;
      const int kp = s >> 4, og = s & 15;
      const int gk = kc + kp * 2, go = o0 + og * 4;
      float4 w0 = *(const float4*)&W0[(size_t)gk * NO + go];
      float4 w1 = *(const float4*)&W0[(size_t)(gk + 1) * NO + go];
      if (WMODE) {
        const float4 m0 = *(const float4*)&W1[(size_t)gk * NO + go];
        const float4 m1 = *(const float4*)&W1[(size_t)(gk + 1) * NO + go];
        w0.x = tanh_fast(w0.x) * sig_fast(m0.x);
        w0.y = tanh_fast(w0.y) * sig_fast(m0.y);
        w0.z = tanh_fast(w0.z) * sig_fast(m0.z);
        w0.w = tanh_fast(w0.w) * sig_fast(m0.w);
        w1.x = tanh_fast(w1.x) * sig_fast(m1.x);
        w1.y = tanh_fast(w1.y) * sig_fast(m1.y);
        w1.z = tanh_fast(w1.z) * sig_fast(m1.z);
        w1.w = tanh_fast(w1.w) * sig_fast(m1.w);
      }
      const float e0[4] = {w0.x, w0.y, w0.z, w0.w};
      const float e1[4] = {w1.x, w1.y, w1.z, w1.w};
#pragma unroll
      for (int j = 0; j < 4; ++j) {
        u16 h0, l0, h1, l1;
        bf16_split(e0[j], h0, l0);
        bf16_split(e1[j], h1, l1);
        const int col = og * 4 + j;
        const int byte = (col * 128 + kp * 4) ^ ((col & 7) << 4);
        *(unsigned*)((char*)BshH + byte) = (unsigned)h0 | ((unsigned)h1 << 16);
        *(unsigned*)((char*)BshL + byte) = (unsigned)l0 | ((unsigned)l1 << 16);
      }
    }
    __syncthreads();
    // ---- compute: 2 k-steps of 32 ----
#pragma unroll
    for (int ks2 = 0; ks2 < 2; ++ks2) {
      const int kb = ((lane >> 4) * 16) + ks2 * 64;
      bf16x8 a_h[2], a_l[2], b_h[4], b_l[4];
#pragma unroll
      for (int m = 0; m < 2; ++m) {
        const int row = w * 32 + m * 16 + (lane & 15);
        const int byte = (row * 128 + kb) ^ ((row & 7) << 4);
        a_h[m] = *(const bf16x8*)((const char*)AshH + byte);
        a_l[m] = *(const bf16x8*)((const char*)AshL + byte);
      }
#pragma unroll
      for (int n = 0; n < 4; ++n) {
        const int col = n * 16 + (lane & 15);
        const int byte = (col * 128 + kb) ^ ((col & 7) << 4);
        b_h[n] = *(const bf16x8*)((const char*)BshH + byte);
        b_l[n] = *(const bf16x8*)((const char*)BshL + byte);
      }
#pragma unroll
      for (int m = 0; m < 2; ++m)
#pragma unroll
        for (int n = 0; n < 4; ++n) {
          acc[m][n] = __builtin_amdgcn_mfma_f32_16x16x32_bf16(a_h[m], b_h[n], acc[m][n], 0, 0, 0);
          acc[m][n] = __builtin_amdgcn_mfma_f32_16x16x32_bf16(a_h[m], b_l[n], acc[m][n], 0, 0, 0);
          acc[m][n] = __builtin_amdgcn_mfma_f32_16x16x32_bf16(a_l[m], b_h[n], acc[m][n], 0, 0, 0);
        }
    }
  }
  // ---- epilogue: C/D layout col=lane&15, row=(lane>>4)*4+reg ----
#pragma unroll
  for (int m = 0; m < 2; ++m)
#pragma unroll
    for (int n = 0; n < 4; ++n) {
      const int col = o0 + n * 16 + (lane & 15);
      const float bv = (ATOMIC && bias) ? bias[col] : 0.f;
#pragma unroll
      for (int r = 0; r < 4; ++r) {
        const int row = w * 32 + m * 16 + (lane >> 4) * 4 + r;
        if (ATOMIC)
          atomicAdd(&outp[(size_t)row * NO + col], acc[m][n][r] + bv);
        else
          outp[(size_t)row * NO + col] = acc[m][n][r];
      }
    }
}

// =============== K1: attn moments (blocks 0..127) + gemmA (blocks 128..255) ===============
__global__ __launch_bounds__(256) void k1_attn_gemmA(
    const float* __restrict__ x, const float* __restrict__ gt,
    const float* __restrict__ wt, const float* __restrict__ mt,
    const float* __restrict__ k1w, const float* __restrict__ embk,
    const float* __restrict__ embb, const float* __restrict__ ekd,
    float* __restrict__ Tfull, float* __restrict__ pA) {
  __shared__ __align__(16) char smem[49152];
  const int bid = blockIdx.x;
  const int t = threadIdx.x;
  if (bid < NB) {
    // ---- attention: T_b = sum_d ekd_d * t[b,d] via tilted moments + Taylor ----
    float* xsh = (float*)smem;                       // 4 KB
    float(*red)[4] = (float(*)[4])(smem + 4096);     // 7x4 floats
    float* bc = (float*)(smem + 4096 + 7 * 4 * 4);   // 9 floats
    *(float4*)&xsh[t * 4] = *(const float4*)&x[bid * ND + t * 4];
    float s1, s3;
    {
      float qk = embk[t], kk = embk[NO + t], qb = embb[t];
      s1 = qk * kk;
      s3 = kk * qb;
      qk = embk[t + 256]; kk = embk[NO + t + 256]; qb = embb[t + 256];
      s1 = fmaf(qk, kk, s1);
      s3 = fmaf(kk, qb, s3);
    }
#pragma unroll
    for (int off = 32; off; off >>= 1) {
      s1 += __shfl_xor(s1, off);
      s3 += __shfl_xor(s3, off);
    }
    const int w = t >> 6;
    if ((t & 63) == 0) { red[0][w] = s1; red[1][w] = s3; }
    __syncthreads();
    if (t < 2) bc[t] = red[t][0] + red[t][1] + red[t][2] + red[t][3];
    __syncthreads();
    const float S1 = bc[0], S3 = bc[1];
    const float aL2 = SCALEQK * LOG2E * S3;  // exp(a*x) = exp2(aL2*x)
    const float dS1 = SCALEQK * S1;          // delta_d = dS1 * x_bd
    float mm[7];
#pragma unroll
    for (int k = 0; k < 7; ++k) mm[k] = 0.f;
#pragma unroll
    for (int j = 0; j < 4; ++j) {
      const float xe = xsh[t * 4 + j];
      float p = fast_exp2(aL2 * xe);
      mm[0] += p;
#pragma unroll
      for (int k = 1; k < 7; ++k) { p *= xe; mm[k] += p; }
    }
#pragma unroll
    for (int off = 32; off; off >>= 1)
#pragma unroll
      for (int k = 0; k < 7; ++k) mm[k] += __shfl_xor(mm[k], off);
    if ((t & 63) == 0)
#pragma unroll
      for (int k = 0; k < 7; ++k) red[k][w] = mm[k];
    __syncthreads();
    if (t < 7) bc[2 + t] = red[t][0] + red[t][1] + red[t][2] + red[t][3];
    __syncthreads();
    const float invf[6] = {1.f, 1.f, 0.5f, 1.6666667e-1f, 4.1666668e-2f, 8.3333333e-3f};
    float cn[6], cd[6];
#pragma unroll
    for (int k = 0; k < 6; ++k) {
      cn[k] = bc[3 + k] * invf[k];  // M_{k+1}/k!
      cd[k] = bc[2 + k] * invf[k];  // M_k/k!
    }
    float Ta = 0.f;
#pragma unroll
    for (int j = 0; j < 4; ++j) {
      const int d = t * 4 + j;
      const float del = dS1 * xsh[d];
      float num = cn[5], den = cd[5];
#pragma unroll
      for (int k = 4; k >= 0; --k) {
        num = fmaf(num, del, cn[k]);
        den = fmaf(den, del, cd[k]);
      }
      Ta = fmaf(ekd[d], num / den, Ta);
    }
#pragma unroll
    for (int off = 32; off; off >>= 1) Ta += __shfl_xor(Ta, off);
    __syncthreads();
    if ((t & 63) == 0) red[0][w] = Ta;
    __syncthreads();
    if (t == 0) Tfull[bid] = red[0][0] + red[0][1] + red[0][2] + red[0][3];
  } else {
    // ---- gemmA: g in {x@k1, x@gt, x@wa, asinh(x)@wa}, ksplit 4 (K-span 256) ----
    const int b2 = bid - NB;
    const int o0 = (b2 & 7) * 64;
    const int ks = (b2 >> 3) & 3;
    const int g = b2 >> 5;
    const int k0 = ks * 256;
    float* outp = pA + (size_t)(g * 4 + ks) * (NB * NO);
    if (g == 0)
      gemm_tile<1, 0, 0, 4>(x, nullptr, nullptr, ND, k1w, k1w, nullptr, outp, o0, k0, smem);
    else if (g == 1)
      gemm_tile<1, 0, 0, 4>(x, nullptr, nullptr, ND, gt, gt, nullptr, outp, o0, k0, smem);
    else if (g == 2)
      gemm_tile<1, 1, 0, 4>(x, nullptr, nullptr, ND, wt, mt, nullptr, outp, o0, k0, smem);
    else
      gemm_tile<2, 1, 0, 4>(x, nullptr, nullptr, ND, wt, mt, nullptr, outp, o0, k0, smem);
  }
}

// =============== K2: combineA -> feat (bf16 h/l) + zero out ===============
__global__ __launch_bounds__(256) void combineA_kernel(
    const float* __restrict__ pA, const float* __restrict__ Tfull,
    const float* __restrict__ bias1, const float* __restrict__ embk,
    const float* __restrict__ embb, const float* __restrict__ ekd,
    const float* __restrict__ ng, const float* __restrict__ nbv,
    u16* __restrict__ featH, u16* __restrict__ featL, float* __restrict__ outz) {
  __shared__ float red[6][4];
  __shared__ float bc[6];
  const int t = threadIdx.x;
  const int p = blockIdx.x * 256 + t;
  const int b = p >> 9, o = p & 511;

  float svk = 0, svb = 0, svk2 = 0, svkvb = 0, svb2 = 0, se = 0;
#pragma unroll
  for (int j = 0; j < 2; ++j) {
    const int oo = t + j * 256;
    const float vk = embk[2 * NO + oo], vb = embb[2 * NO + oo];
    svk += vk; svb += vb;
    svk2 = fmaf(vk, vk, svk2);
    svkvb = fmaf(vk, vb, svkvb);
    svb2 = fmaf(vb, vb, svb2);
  }
#pragma unroll
  for (int j = 0; j < 4; ++j) se += ekd[t + j * 256];
#pragma unroll
  for (int off = 32; off; off >>= 1) {
    svk += __shfl_xor(svk, off); svb += __shfl_xor(svb, off);
    svk2 += __shfl_xor(svk2, off); svkvb += __shfl_xor(svkvb, off);
    svb2 += __shfl_xor(svb2, off); se += __shfl_xor(se, off);
  }
  const int w = t >> 6;
  if ((t & 63) == 0) {
    red[0][w] = svk; red[1][w] = svb; red[2][w] = svk2;
    red[3][w] = svkvb; red[4][w] = svb2; red[5][w] = se;
  }
  __syncthreads();
  if (t < 6) bc[t] = red[t][0] + red[t][1] + red[t][2] + red[t][3];
  __syncthreads();
  const float inv_o = 1.f / (float)NO;
  const float mvk = bc[0] * inv_o, mvb = bc[1] * inv_o;
  const float Mvk2 = bc[2] * inv_o - mvk * mvk;
  const float Mvkvb = bc[3] * inv_o - mvk * mvb;
  const float Mvb2 = bc[4] * inv_o - mvb * mvb;
  const float E = bc[5];

  float d1 = 0, d2 = 0, d3 = 0, d4 = 0;
#pragma unroll
  for (int ks = 0; ks < 4; ++ks) {
    d1 += pA[((size_t)(0 * 4 + ks) * NB + b) * NO + o];
    d2 += pA[((size_t)(1 * 4 + ks) * NB + b) * NO + o];
    d3 += pA[((size_t)(2 * 4 + ks) * NB + b) * NO + o];
    d4 += pA[((size_t)(3 * 4 + ks) * NB + b) * NO + o];
  }
  const float c1v = d1 + bias1[o];
  const float gg = sig_fast(d2);
  const float mmv = sinhf(d4);
  const float c3v = fmaf(gg, d3 - mmv, mmv);
  const float T = Tfull[b];
  const float vkc = embk[2 * NO + o] - mvk, vbc = embb[2 * NO + o] - mvb;
  const float var = T * T * Mvk2 + 2.f * T * E * Mvkvb + E * E * Mvb2;
  const float c4v = (T * vkc + E * vbc) * rsqrtf(var + EPSV) * ng[o] + nbv[o];

  u16* fH = featH + (size_t)b * NK3;
  u16* fL = featL + (size_t)b * NK3;
  u16 h, l;
  bf16_split(c1v, h, l); fH[o] = h; fL[o] = l;
  bf16_split(c3v, h, l); fH[NO + o] = h; fL[NO + o] = l;
  bf16_split(c4v, h, l); fH[2 * NO + o] = h; fL[2 * NO + o] = l;
  outz[p] = 0.f;  // zero output for K3's atomic accumulation
}

// =============== K3: gemmB feat[128,1536] @ k3[1536,512], atomic into out ===============
__global__ __launch_bounds__(256) void k3_gemmB(
    const u16* __restrict__ fh, const u16* __restrict__ fl,
    const float* __restrict__ k3w, const float* __restrict__ b3,
    float* __restrict__ out) {
  __shared__ __align__(16) char smem[49152];
  const int o0 = (blockIdx.x & 7) * 64;
  const int ks = blockIdx.x >> 3;
  gemm_tile<0, 0, 1, 2>(nullptr, fh, fl, NK3, k3w, k3w, (ks == 0) ? b3 : nullptr,
                        out, o0, ks * 128, smem);
}

extern "C" void kernel_launch(void* const* d_in, const int* in_sizes, int n_in,
                              void* d_out, int out_size, void* d_ws, size_t ws_size,
                              hipStream_t stream) {
  const float* x    = (const float*)d_in[0];
  const float* gt   = (const float*)d_in[1];
  const float* wt   = (const float*)d_in[2];
  const float* mt   = (const float*)d_in[3];
  const float* k1   = (const float*)d_in[4];
  const float* b1   = (const float*)d_in[5];
  const float* k3   = (const float*)d_in[6];
  const float* b3   = (const float*)d_in[7];
  const float* embk = (const float*)d_in[8];
  const float* embb = (const float*)d_in[9];
  const float* ekd  = (const float*)d_in[10];
  const float* ng   = (const float*)d_in[11];
  const float* nb   = (const float*)d_in[12];

  char* wsb = (char*)d_ws;
  float* Tfull = (float*)wsb;                          // 512 B
  float* pA = (float*)(wsb + 4096);                    // 16*128*512*4 = 4 MB
  u16* featH = (u16*)(wsb + 4096 + (4u << 20));        // 384 KB
  u16* featL = (u16*)(wsb + 4096 + (4u << 20) + (512u << 10));
  float* out = (float*)d_out;

  hipLaunchKernelGGL(k1_attn_gemmA, dim3(256), dim3(256), 0, stream,
                     x, gt, wt, mt, k1, embk, embb, ekd, Tfull, pA);
  hipLaunchKernelGGL(combineA_kernel, dim3(256), dim3(256), 0, stream,
                     pA, Tfull, b1, embk, embb, ekd, ng, nb, featH, featL, out);
  hipLaunchKernelGGL(k3_gemmB, dim3(96), dim3(256), 0, stream,
                     featH, featL, k3, b3, out);
}